// Round 4
// baseline (11192.220 us; speedup 1.0000x reference)
//
#include <hip/hip_runtime.h>

// TextDecoder: 2-layer LSTM, B=64, H=1024, V=10000, T=32 (31 computed steps).
// Round 5: attack the measured flat ~475 GB/s memory wall (rounds 1&3 both
// pinned there; duration scaled linearly with bytes).
//  - Weights stored FRAGMENT-CONTIGUOUS: [n-tile 32][k-block 32][half][lane][8]
//    so each MFMA B-load is one contiguous 1 KB wave burst (was 16 lines
//    scattered 2 KB apart -> miss-concurrency saturation).
//  - m-dedup: per-wave jobs are 64 A-rows x 32 W-rows: each weight byte read
//    ONCE per step (~81 MB/step vs ~100 measured).
//  - Non-temporal loads/stores for single-use partial slabs and `out`.
//  - Persistent kernel, 256 blocks x 512 threads; round-1-proven counter
//    barrier verbatim. Phases: P1 [logits-reduce(t-1)+argmax+cell0] |
//    P2 [L1 gemms + L0(t+1) gemm, 1536 jobs] | P3 cell1 | P4 logits KS=4.

#define HDIM 1024
#define BDIM 64
#define VDIM 10000
#define VPAD 10048   // 314 * 32
#define NTSQ 128     // n-tiles in a 4096-row weight
#define NTOUT 314    // n-tiles in Wout (VPAD rows)
#define TDIM 32
#define NB   256
#define BS   512

typedef _Float16 f16;
typedef _Float16 f16x8 __attribute__((ext_vector_type(8)));
typedef float f32x4 __attribute__((ext_vector_type(4)));

// ---- workspace layout (bytes); total 98,635,776 <= proven ws_size >= 101,450,752
#define WS_C1    0              // 64x1024 f32
#define WS_C2    262144
#define WS_H1H   524288         // 64x1024 f16 each
#define WS_H1L   655360
#define WS_H2H   786432
#define WS_H2L   917504
#define WS_PRE0  1048576        // 4 slabs x [64][4096] f32 (L0 partials)
#define WS_PRE1  5242880        // shared region, 10,289,152 B:
                                //   P2/P3: 8 slabs x [64][4096] f32 (L1 partials)
                                //   P4/P1: 4 slabs x [64][VPAD] f32 (logits partials)
#define WS_BAR   15532032       // 256 B barrier state (memset 0 per call)
#define WS_WB    15536128       // swizzled converted weights
#define SQB      8388608        // one swizzled 4096x1024 f16 matrix
#define WOB      20578304       // one swizzled VPADx1024 f16 matrix
#define SLAB     262144         // floats per [64][4096] slab
#define LSLAB    643072         // floats per [64][VPAD] slab

__device__ __forceinline__ float sigmoidf_(float x) {
    return 1.0f / (1.0f + expf(-x));
}

// Counter grid barrier — EXACT code that passed on HW (rounds 1 and 3).
__device__ __forceinline__ void gridbar(int* bar) {
    __syncthreads();
    if (threadIdx.x == 0) {
        __threadfence();
        int g = __hip_atomic_load(bar + 32, __ATOMIC_RELAXED, __HIP_MEMORY_SCOPE_AGENT);
        int a = __hip_atomic_fetch_add(bar, 1, __ATOMIC_ACQ_REL, __HIP_MEMORY_SCOPE_AGENT);
        if (a == NB - 1) {
            __hip_atomic_store(bar, 0, __ATOMIC_RELAXED, __HIP_MEMORY_SCOPE_AGENT);
            __hip_atomic_fetch_add(bar + 32, 1, __ATOMIC_RELEASE, __HIP_MEMORY_SCOPE_AGENT);
        } else {
            while (__hip_atomic_load(bar + 32, __ATOMIC_ACQUIRE, __HIP_MEMORY_SCOPE_AGENT) == g)
                __builtin_amdgcn_s_sleep(4);
        }
    }
    __syncthreads();
}

// ------------------------------------------------------------------
// Swizzled weight layout: f16 element index
//   idx(nt,kb,c,lane,e) = nt*32768 + kb*1024 + c*512 + lane*8 + e
//   <-> row = nt*32 + c*16 + (lane&15), col = kb*32 + (lane>>4)*8 + e
// A wave's B-fragment load (one kb, one c) = contiguous 1 KB.
// ------------------------------------------------------------------

// Per-wave 64x32 split-fp16 MFMA job: A (natural layout, hi+lo) rows 0..63,
// W (swizzled, lo only if WSPLIT) n-tile nt, k-blocks kb0..kb0+7 (k-len 256).
// C layout (HW-verified): row = mt*16 + quad*4 + r, col = colbase + c*16 + lm.
template <bool WSPLIT>
__device__ __forceinline__ void wgemm64(
    const f16* __restrict__ Ah, const f16* __restrict__ Al,
    const f16* __restrict__ Wsh, const f16* __restrict__ Wsl,
    int nt, int kb0, float* __restrict__ dst, int ldd, int colbase)
{
    const int lane = threadIdx.x & 63;
    const int lm = lane & 15, quad = lane >> 4;
    f32x4 acc[4][2] = {};
    f32x4 accL[4][2] = {};
    const f16* a_h = Ah + (size_t)lm * HDIM + kb0 * 32 + quad * 8;
    const f16* a_l = Al + (size_t)lm * HDIM + kb0 * 32 + quad * 8;
    const f16* w_h = Wsh + (size_t)nt * 32768 + (size_t)kb0 * 1024 + lane * 8;
    const f16* w_l = WSPLIT ? (Wsl + (size_t)nt * 32768 + (size_t)kb0 * 1024 + lane * 8)
                            : (const f16*)nullptr;
    #pragma unroll 2
    for (int kb = 0; kb < 8; kb++) {
        f16x8 bh0 = *(const f16x8*)(w_h + kb * 1024);
        f16x8 bh1 = *(const f16x8*)(w_h + kb * 1024 + 512);
        f16x8 ah[4], al[4];
        #pragma unroll
        for (int mt = 0; mt < 4; mt++) {
            ah[mt] = *(const f16x8*)(a_h + mt * (16 * HDIM) + kb * 32);
            al[mt] = *(const f16x8*)(a_l + mt * (16 * HDIM) + kb * 32);
        }
        #pragma unroll
        for (int mt = 0; mt < 4; mt++) {
            acc[mt][0]  = __builtin_amdgcn_mfma_f32_16x16x32_f16(ah[mt], bh0, acc[mt][0], 0, 0, 0);
            acc[mt][1]  = __builtin_amdgcn_mfma_f32_16x16x32_f16(ah[mt], bh1, acc[mt][1], 0, 0, 0);
            accL[mt][0] = __builtin_amdgcn_mfma_f32_16x16x32_f16(al[mt], bh0, accL[mt][0], 0, 0, 0);
            accL[mt][1] = __builtin_amdgcn_mfma_f32_16x16x32_f16(al[mt], bh1, accL[mt][1], 0, 0, 0);
        }
        if constexpr (WSPLIT) {
            f16x8 bl0 = *(const f16x8*)(w_l + kb * 1024);
            f16x8 bl1 = *(const f16x8*)(w_l + kb * 1024 + 512);
            #pragma unroll
            for (int mt = 0; mt < 4; mt++) {
                accL[mt][0] = __builtin_amdgcn_mfma_f32_16x16x32_f16(ah[mt], bl0, accL[mt][0], 0, 0, 0);
                accL[mt][1] = __builtin_amdgcn_mfma_f32_16x16x32_f16(ah[mt], bl1, accL[mt][1], 0, 0, 0);
            }
        }
    }
    #pragma unroll
    for (int mt = 0; mt < 4; mt++)
        #pragma unroll
        for (int c = 0; c < 2; c++)
            #pragma unroll
            for (int r = 0; r < 4; r++) {
                int row = mt * 16 + quad * 4 + r;
                int col = colbase + c * 16 + lm;
                __builtin_nontemporal_store(
                    acc[mt][c][r] + accL[mt][c][r] * (1.0f / 2048.0f),
                    &dst[(size_t)row * ldd + col]);
            }
}

// fp32 [srcRows x 1024] -> swizzled hi (and lo*2048 if lo != null), NT n-tiles,
// zero-padding rows >= srcRows. Writes are fully coalesced (16 B/thread).
__device__ void conv_swz(const float* __restrict__ src,
                         f16* __restrict__ hi, f16* __restrict__ lo,
                         int NT, int srcRows, int gt)
{
    int total = NT * 4096;   // octets
    for (int o = gt; o < total; o += NB * BS) {
        int lane = o & 63, c = (o >> 6) & 1, kb = (o >> 7) & 31, nt = o >> 12;
        int row = nt * 32 + c * 16 + (lane & 15);
        int col = kb * 32 + ((lane >> 4) << 3);
        float f[8] = {};
        if (row < srcRows) {
            float4 v0 = *(const float4*)(src + (size_t)row * HDIM + col);
            float4 v1 = *(const float4*)(src + (size_t)row * HDIM + col + 4);
            f[0] = v0.x; f[1] = v0.y; f[2] = v0.z; f[3] = v0.w;
            f[4] = v1.x; f[5] = v1.y; f[6] = v1.z; f[7] = v1.w;
        }
        f16x8 H, L;
        #pragma unroll
        for (int e = 0; e < 8; e++) {
            f16 h = (f16)f[e];
            H[e] = h;
            L[e] = (f16)((f[e] - (float)h) * 2048.0f);
        }
        *(f16x8*)(hi + (size_t)o * 8) = H;
        if (lo) *(f16x8*)(lo + (size_t)o * 8) = L;
    }
}

__global__ __launch_bounds__(BS) void decode_all(
    const float* __restrict__ hidden, const float* __restrict__ cellin,
    const int* __restrict__ captions, const int* __restrict__ tfmask,
    const float* __restrict__ Wih0, const float* __restrict__ Whh0,
    const float* __restrict__ bih0, const float* __restrict__ bhh0,
    const float* __restrict__ Wih1, const float* __restrict__ Whh1,
    const float* __restrict__ bih1, const float* __restrict__ bhh1,
    const float* __restrict__ Wout, const float* __restrict__ bout,
    float* __restrict__ out, char* __restrict__ wsb)
{
    const int tid = threadIdx.x, bid = blockIdx.x;
    const int jslot = (tid >> 6) * NB + bid;   // wave-job slot, 0..2047

    float* c1 = (float*)(wsb + WS_C1);
    float* c2 = (float*)(wsb + WS_C2);
    f16* h1h = (f16*)(wsb + WS_H1H);
    f16* h1l = (f16*)(wsb + WS_H1L);
    f16* h2h = (f16*)(wsb + WS_H2H);
    f16* h2l = (f16*)(wsb + WS_H2L);
    float* pre0 = (float*)(wsb + WS_PRE0);
    float* pre1 = (float*)(wsb + WS_PRE1);
    float* logb = (float*)(wsb + WS_PRE1);     // aliases pre1 (disjoint lifetime)
    int* bar = (int*)(wsb + WS_BAR);
    f16* Whh0h = (f16*)(wsb + WS_WB);
    f16* Wih1h = (f16*)(wsb + WS_WB + 1 * (size_t)SQB);
    f16* Wih1l = (f16*)(wsb + WS_WB + 2 * (size_t)SQB);
    f16* Whh1h = (f16*)(wsb + WS_WB + 3 * (size_t)SQB);
    f16* Whh1l = (f16*)(wsb + WS_WB + 4 * (size_t)SQB);
    f16* Wouth = (f16*)(wsb + WS_WB + 5 * (size_t)SQB);
    f16* Woutl = (f16*)(wsb + WS_WB + 5 * (size_t)SQB + (size_t)WOB);

    __shared__ unsigned long long red_s[8];
    __shared__ int tok_s;

    // ---------------- phase 0: weight conversion (swizzled) + state init ----------------
    {
        const int gt = bid * BS + tid;
        conv_swz(Whh0, Whh0h, (f16*)0, NTSQ, 4096, gt);
        conv_swz(Wih1, Wih1h, Wih1l, NTSQ, 4096, gt);
        conv_swz(Whh1, Whh1h, Whh1l, NTSQ, 4096, gt);
        conv_swz(Wout, Wouth, Woutl, NTOUT, VDIM, gt);
        for (int i = gt; i < BDIM * HDIM; i += NB * BS) {   // states
            float a = hidden[i], b = hidden[BDIM * HDIM + i];
            f16 ah = (f16)a, bh = (f16)b;
            h1h[i] = ah; h1l[i] = (f16)((a - (float)ah) * 2048.0f);
            h2h[i] = bh; h2l[i] = (f16)((b - (float)bh) * 2048.0f);
            c1[i] = cellin[i];
            c2[i] = cellin[BDIM * HDIM + i];
        }
        for (int i = gt; i < BDIM * VDIM; i += NB * BS) {   // out[:,0,:] one-hot
            int b = i / VDIM, v = i - b * VDIM;
            __builtin_nontemporal_store(
                (v == captions[b * TDIM]) ? 1.0f : 0.0f,
                &out[(size_t)b * (TDIM * VDIM) + v]);
        }
    }
    gridbar(bar);

    // ------------- prologue: L0 h-gemm for t=1 (512 wave-jobs, KS=4) -------------
    if (jslot < 512) {
        int nt = jslot >> 2, q = jslot & 3;
        wgemm64<false>(h1h, h1l, Whh0h, (const f16*)0, nt, q * 8,
                       pre0 + (size_t)q * SLAB, 4096, nt * 32);
    }
    gridbar(bar);

    for (int t = 1; t < TDIM; t++) {
        // ---- P1: fused logits-reduce(t-1) + out + argmax + cell0 (64 row-blocks) ----
        if (bid < BDIM) {
            const int b = bid;
            int tok;
            if (t > 1) {
                const float* l0 = logb + (size_t)b * VPAD;
                float* orow = out + (size_t)b * (TDIM * VDIM) + (size_t)(t - 1) * VDIM;
                unsigned long long best = 0ull;
                for (int c = tid; c < VDIM; c += BS) {
                    float sv = __builtin_nontemporal_load(&l0[c])
                             + __builtin_nontemporal_load(&l0[LSLAB + c])
                             + __builtin_nontemporal_load(&l0[2 * LSLAB + c])
                             + __builtin_nontemporal_load(&l0[3 * LSLAB + c])
                             + bout[c];
                    __builtin_nontemporal_store(sv, &orow[c]);
                    unsigned u = __float_as_uint(sv);
                    u = (u & 0x80000000u) ? ~u : (u | 0x80000000u);
                    unsigned long long p = ((unsigned long long)u << 32) | (unsigned)(~c);
                    if (p > best) best = p;
                }
                #pragma unroll
                for (int m = 32; m > 0; m >>= 1) {
                    unsigned long long o = __shfl_down(best, m, 64);
                    if (o > best) best = o;
                }
                if ((tid & 63) == 0) red_s[tid >> 6] = best;
                __syncthreads();
                if (tid == 0) {
                    best = red_s[0];
                    #pragma unroll
                    for (int w = 1; w < 8; w++) if (red_s[w] > best) best = red_s[w];
                    tok_s = (int)(~(unsigned)(best & 0xffffffffull));
                }
                __syncthreads();
                tok = (tfmask[t - 1] != 0) ? captions[b * TDIM + (t - 1)] : tok_s;
            } else {
                tok = captions[b * TDIM];
            }
            #pragma unroll
            for (int ii = 0; ii < 2; ii++) {
                int i = ii * BS + tid;
                float g[4];
                #pragma unroll
                for (int gi = 0; gi < 4; gi++) {
                    int j = (gi << 10) + i;
                    float s = bih0[j] + bhh0[j] + Wih0[(size_t)j * VDIM + tok];
                    #pragma unroll
                    for (int q = 0; q < 4; q++)
                        s += __builtin_nontemporal_load(&pre0[q * SLAB + (b << 12) + j]);
                    g[gi] = s;
                }
                int idx = (b << 10) + i;
                float ig = sigmoidf_(g[0]), fg = sigmoidf_(g[1]);
                float gg = tanhf(g[2]),     og = sigmoidf_(g[3]);
                float cn = fg * c1[idx] + ig * gg;
                float hn = og * tanhf(cn);
                c1[idx] = cn;
                f16 hh = (f16)hn;
                h1h[idx] = hh;
                h1l[idx] = (f16)((hn - (float)hh) * 2048.0f);
            }
        }
        gridbar(bar);

        // ---- P2: L1 gemms (1024 jobs) + L0 gemm for t+1 (512 jobs) ----
        if (jslot < 512) {                       // z=0: h1 @ Wih1
            int nt = jslot >> 2, q = jslot & 3;
            wgemm64<true>(h1h, h1l, Wih1h, Wih1l, nt, q * 8,
                          pre1 + (size_t)q * SLAB, 4096, nt * 32);
        } else if (jslot < 1024) {               // z=1: h2 @ Whh1
            int u = jslot - 512;
            int nt = u >> 2, q = u & 3;
            wgemm64<true>(h2h, h2l, Whh1h, Whh1l, nt, q * 8,
                          pre1 + (size_t)(4 + q) * SLAB, 4096, nt * 32);
        } else if (jslot < 1536 && t < TDIM - 1) {  // L0 prefetch: h1 @ Whh0
            int u = jslot - 1024;
            int nt = u >> 2, q = u & 3;
            wgemm64<false>(h1h, h1l, Whh0h, (const f16*)0, nt, q * 8,
                           pre0 + (size_t)q * SLAB, 4096, nt * 32);
        }
        gridbar(bar);

        // ---- P3: cell1 (one element per thread, blocks 0..127) ----
        {
            int e = bid * BS + tid;
            if (e < BDIM * HDIM) {
                int b = e >> 10, i = e & 1023;
                float g[4];
                #pragma unroll
                for (int gi = 0; gi < 4; gi++) {
                    int j = (gi << 10) + i;
                    float s = bih1[j] + bhh1[j];
                    #pragma unroll
                    for (int q = 0; q < 8; q++)
                        s += __builtin_nontemporal_load(&pre1[q * SLAB + (b << 12) + j]);
                    g[gi] = s;
                }
                float ig = sigmoidf_(g[0]), fg = sigmoidf_(g[1]);
                float gg = tanhf(g[2]),     og = sigmoidf_(g[3]);
                float cn = fg * c2[e] + ig * gg;
                float hn = og * tanhf(cn);
                c2[e] = cn;
                f16 hh = (f16)hn;
                h2h[e] = hh;
                h2l[e] = (f16)((hn - (float)hh) * 2048.0f);
            }
        }
        gridbar(bar);

        // ---- P4: logits gemm, KS=4 (1256 jobs) ----
        if (jslot < 1256) {
            int nt = jslot >> 2, q = jslot & 3;
            wgemm64<true>(h2h, h2l, Wouth, Woutl, nt, q * 8,
                          logb + (size_t)q * LSLAB, VPAD, nt * 32);
        }
        gridbar(bar);
    }

    // ---------------- epilogue: out[:,31,:] = logits(t=31) + bias ----------------
    for (int g = bid * BS + tid; g < BDIM * VDIM; g += NB * BS) {
        int b = g / VDIM, c = g - b * VDIM;
        float sv = logb[(size_t)b * VPAD + c]
                 + logb[LSLAB + (size_t)b * VPAD + c]
                 + logb[2 * LSLAB + (size_t)b * VPAD + c]
                 + logb[3 * LSLAB + (size_t)b * VPAD + c] + bout[c];
        __builtin_nontemporal_store(
            sv, &out[(size_t)b * (TDIM * VDIM) + (size_t)(TDIM - 1) * VDIM + c]);
    }
}

extern "C" void kernel_launch(void* const* d_in, const int* in_sizes, int n_in,
                              void* d_out, int out_size, void* d_ws, size_t ws_size,
                              hipStream_t stream)
{
    const float* hidden   = (const float*)d_in[0];
    const float* cellin   = (const float*)d_in[1];
    const int*   captions = (const int*)d_in[2];
    const int*   tfmask   = (const int*)d_in[3];
    const float* Wih0 = (const float*)d_in[4];
    const float* Whh0 = (const float*)d_in[5];
    const float* bih0 = (const float*)d_in[6];
    const float* bhh0 = (const float*)d_in[7];
    const float* Wih1 = (const float*)d_in[8];
    const float* Whh1 = (const float*)d_in[9];
    const float* bih1 = (const float*)d_in[10];
    const float* bhh1 = (const float*)d_in[11];
    const float* Wout = (const float*)d_in[12];
    const float* bout = (const float*)d_in[13];

    char* wsb = (char*)d_ws;
    // zero barrier state (ws is re-poisoned each call)
    hipMemsetAsync(wsb + WS_BAR, 0, 256, stream);
    decode_all<<<NB, BS, 0, stream>>>(hidden, cellin, captions, tfmask,
                                      Wih0, Whh0, bih0, bhh0,
                                      Wih1, Whh1, bih1, bhh1,
                                      Wout, bout, (float*)d_out, wsb);
}

// Round 5
// 2335.368 us; speedup vs baseline: 4.7925x; 4.7925x over previous
//
#include <hip/hip_runtime.h>

// TextDecoder: 2-layer LSTM, B=64, H=1024, V=10000, T=32 (31 computed steps).
// Round 6: REVERT to the launched multi-kernel structure (round-0, 3013 us,
// measured ~1.2 TB/s effective weight stream) — every persistent-kernel
// variant ran its memory stream 2-3x slower (475 -> 376 GB/s) regardless of
// occupancy/swizzle/NT. Changes vs round-0, all byte/launch cuts:
//  - W-side lo dropped for Whh0 (rounds 3/4: absmax-neutral) and Wih1/Whh1
//    (error ~1e-4 into gate preacts). A-side hi+lo kept; Wout keeps hi+lo.
//    Weight stream 89 -> 65 MB/step.
//  - Logits GEMM KS=1 with fused epilogue: writes out+bias directly plus
//    per-64-col argmax candidates; sumarg kernel and ~10 MB/step of logits
//    partial round-trip eliminated. cell0 reduces the 157 candidates.
//  - L0 GEMM for t+1 fused into the logits kernel as extra blocks
//    (depends only on h1(t)): 4 launches/step instead of 6.

#define HDIM 1024
#define BDIM 64
#define VDIM 10000
#define VPAD 10048   // 157 * 64
#define TDIM 32

typedef _Float16 f16;
typedef _Float16 f16x8 __attribute__((ext_vector_type(8)));
typedef float f32x4 __attribute__((ext_vector_type(4)));

// ---- workspace layout (bytes); total ~80.0 MB <= proven ws_size >= 101,450,752
#define WS_C1    0              // 64x1024 f32
#define WS_C2    262144
#define WS_H1H   524288         // 64x1024 f16 each
#define WS_H1L   655360
#define WS_H2H   786432
#define WS_H2L   917504
#define WS_CAND  1048576        // 64 x 157 u64 candidates (80,384 B)
#define WS_PRE0  1130496        // 4 slabs x [64][4096] f32 (L0 partials)
#define WS_PRE1  5324800        // 8 slabs x [64][4096] f32 (L1 partials)
#define WS_WB    13713408       // converted weights
#define SQB      8388608        // 4096x1024 f16
#define WVO      20578304       // VPADx1024 f16

__device__ __forceinline__ float sigmoidf_(float x) {
    return 1.0f / (1.0f + expf(-x));
}

// ------------------------------------------------------------------
// A-split-only MFMA GEMM: part[slab] = A(hi+lo/2048) @ W(hi)^T, K-quarter q.
// Block = 64x64 tile (2x2 waves of 32x32), fragments straight from global.
// C layout (HW-verified): row = m0 + rt*16 + quad*4 + r, col = n0 + ct*16 + lm.
// ------------------------------------------------------------------
__global__ __launch_bounds__(256) void gemm_as(
    const f16* __restrict__ Ah0, const f16* __restrict__ Al0,
    const f16* __restrict__ Wh0,
    const f16* __restrict__ Ah1, const f16* __restrict__ Al1,
    const f16* __restrict__ Wh1,
    float* __restrict__ part, int KS)
{
    const int tid = threadIdx.x;
    const int wave = tid >> 6, lane = tid & 63;
    const int wr = wave >> 1, wc = wave & 1;
    const int q = blockIdx.y, z = blockIdx.z;
    const f16* __restrict__ Ah = z ? Ah1 : Ah0;
    const f16* __restrict__ Al = z ? Al1 : Al0;
    const f16* __restrict__ Wh = z ? Wh1 : Wh0;
    const int klen = HDIM / KS;
    const int kbase = q * klen;
    const int n0 = blockIdx.x * 64 + wc * 32;
    const int m0 = wr * 32;
    const int lm = lane & 15, quad = lane >> 4;
    const int slab = z * KS + q;

    f32x4 acc[2][2] = {};
    f32x4 accL[2][2] = {};

    const f16* a_h = Ah + (size_t)(m0 + lm) * HDIM + kbase + quad * 8;
    const f16* a_l = Al + (size_t)(m0 + lm) * HDIM + kbase + quad * 8;
    const f16* b_h = Wh + (size_t)(n0 + lm) * HDIM + kbase + quad * 8;

    #pragma unroll 4
    for (int ko = 0; ko < klen; ko += 32) {
        f16x8 ah0 = *(const f16x8*)(a_h + ko);
        f16x8 ah1 = *(const f16x8*)(a_h + 16 * HDIM + ko);
        f16x8 al0 = *(const f16x8*)(a_l + ko);
        f16x8 al1 = *(const f16x8*)(a_l + 16 * HDIM + ko);
        f16x8 bh0 = *(const f16x8*)(b_h + ko);
        f16x8 bh1 = *(const f16x8*)(b_h + 16 * HDIM + ko);

        acc[0][0] = __builtin_amdgcn_mfma_f32_16x16x32_f16(ah0, bh0, acc[0][0], 0, 0, 0);
        acc[0][1] = __builtin_amdgcn_mfma_f32_16x16x32_f16(ah0, bh1, acc[0][1], 0, 0, 0);
        acc[1][0] = __builtin_amdgcn_mfma_f32_16x16x32_f16(ah1, bh0, acc[1][0], 0, 0, 0);
        acc[1][1] = __builtin_amdgcn_mfma_f32_16x16x32_f16(ah1, bh1, acc[1][1], 0, 0, 0);

        accL[0][0] = __builtin_amdgcn_mfma_f32_16x16x32_f16(al0, bh0, accL[0][0], 0, 0, 0);
        accL[0][1] = __builtin_amdgcn_mfma_f32_16x16x32_f16(al0, bh1, accL[0][1], 0, 0, 0);
        accL[1][0] = __builtin_amdgcn_mfma_f32_16x16x32_f16(al1, bh0, accL[1][0], 0, 0, 0);
        accL[1][1] = __builtin_amdgcn_mfma_f32_16x16x32_f16(al1, bh1, accL[1][1], 0, 0, 0);
    }

    float* dst = part + (size_t)slab * 262144;
    #pragma unroll
    for (int rt = 0; rt < 2; rt++)
        #pragma unroll
        for (int ct = 0; ct < 2; ct++)
            #pragma unroll
            for (int r = 0; r < 4; r++) {
                int row = m0 + rt * 16 + quad * 4 + r;
                int col = n0 + ct * 16 + lm;
                dst[(size_t)row * 4096 + col] =
                    acc[rt][ct][r] + accL[rt][ct][r] * (1.0f / 2048.0f);
            }
}

// ------------------------------------------------------------------
// Fused: blocks 0..156 -> logits (full-K, hi/lo W, writes out+bias directly,
// emits per-64-col argmax candidates); blocks 157..412 -> L0 h-gemm for the
// NEXT step (A=h1 splits, W=Whh0 hi, KS=4 -> pre0).
// ------------------------------------------------------------------
__global__ __launch_bounds__(256) void gemm_out_l0(
    const f16* __restrict__ h2h, const f16* __restrict__ h2l,
    const f16* __restrict__ Wouth, const f16* __restrict__ Woutl,
    const float* __restrict__ bout, float* __restrict__ out,
    unsigned long long* __restrict__ cand, int t,
    const f16* __restrict__ h1h, const f16* __restrict__ h1l,
    const f16* __restrict__ Whh0h, float* __restrict__ pre0)
{
    const int tid = threadIdx.x;
    const int wave = tid >> 6, lane = tid & 63;
    const int wr = wave >> 1, wc = wave & 1;
    const int lm = lane & 15, quad = lane >> 4;
    const int bx = blockIdx.x;

    if (bx < 157) {
        // ---------------- logits path: 64 rows x 64 cols, K = 1024 ----------------
        const int n0 = bx * 64 + wc * 32;
        const int m0 = wr * 32;
        f32x4 acc[2][2] = {};
        f32x4 accL[2][2] = {};
        const f16* a_h = h2h + (size_t)(m0 + lm) * HDIM + quad * 8;
        const f16* a_l = h2l + (size_t)(m0 + lm) * HDIM + quad * 8;
        const f16* b_h = Wouth + (size_t)(n0 + lm) * HDIM + quad * 8;
        const f16* b_l = Woutl + (size_t)(n0 + lm) * HDIM + quad * 8;

        #pragma unroll 4
        for (int ko = 0; ko < HDIM; ko += 32) {
            f16x8 ah0 = *(const f16x8*)(a_h + ko);
            f16x8 ah1 = *(const f16x8*)(a_h + 16 * HDIM + ko);
            f16x8 al0 = *(const f16x8*)(a_l + ko);
            f16x8 al1 = *(const f16x8*)(a_l + 16 * HDIM + ko);
            f16x8 bh0 = *(const f16x8*)(b_h + ko);
            f16x8 bh1 = *(const f16x8*)(b_h + 16 * HDIM + ko);
            f16x8 bl0 = *(const f16x8*)(b_l + ko);
            f16x8 bl1 = *(const f16x8*)(b_l + 16 * HDIM + ko);

            acc[0][0] = __builtin_amdgcn_mfma_f32_16x16x32_f16(ah0, bh0, acc[0][0], 0, 0, 0);
            acc[0][1] = __builtin_amdgcn_mfma_f32_16x16x32_f16(ah0, bh1, acc[0][1], 0, 0, 0);
            acc[1][0] = __builtin_amdgcn_mfma_f32_16x16x32_f16(ah1, bh0, acc[1][0], 0, 0, 0);
            acc[1][1] = __builtin_amdgcn_mfma_f32_16x16x32_f16(ah1, bh1, acc[1][1], 0, 0, 0);

            accL[0][0] = __builtin_amdgcn_mfma_f32_16x16x32_f16(ah0, bl0, accL[0][0], 0, 0, 0);
            accL[0][1] = __builtin_amdgcn_mfma_f32_16x16x32_f16(ah0, bl1, accL[0][1], 0, 0, 0);
            accL[1][0] = __builtin_amdgcn_mfma_f32_16x16x32_f16(ah1, bl0, accL[1][0], 0, 0, 0);
            accL[1][1] = __builtin_amdgcn_mfma_f32_16x16x32_f16(ah1, bl1, accL[1][1], 0, 0, 0);

            accL[0][0] = __builtin_amdgcn_mfma_f32_16x16x32_f16(al0, bh0, accL[0][0], 0, 0, 0);
            accL[0][1] = __builtin_amdgcn_mfma_f32_16x16x32_f16(al0, bh1, accL[0][1], 0, 0, 0);
            accL[1][0] = __builtin_amdgcn_mfma_f32_16x16x32_f16(al1, bh0, accL[1][0], 0, 0, 0);
            accL[1][1] = __builtin_amdgcn_mfma_f32_16x16x32_f16(al1, bh1, accL[1][1], 0, 0, 0);
        }

        __shared__ unsigned long long cs[64][2];
        float bo[2];
        #pragma unroll
        for (int ct = 0; ct < 2; ct++) {
            int col = n0 + ct * 16 + lm;
            bo[ct] = (col < VDIM) ? bout[col] : 0.0f;
        }
        #pragma unroll
        for (int rt = 0; rt < 2; rt++)
            #pragma unroll
            for (int r = 0; r < 4; r++) {
                int row = m0 + rt * 16 + quad * 4 + r;
                unsigned long long e = 0ull;
                #pragma unroll
                for (int ct = 0; ct < 2; ct++) {
                    int col = n0 + ct * 16 + lm;
                    if (col < VDIM) {
                        float s = acc[rt][ct][r] + accL[rt][ct][r] * (1.0f / 2048.0f)
                                + bo[ct];
                        out[(size_t)row * (TDIM * VDIM) + (size_t)t * VDIM + col] = s;
                        unsigned u = __float_as_uint(s);
                        u = (u & 0x80000000u) ? ~u : (u | 0x80000000u);
                        unsigned long long p =
                            ((unsigned long long)u << 32) | (unsigned)(~col);
                        if (p > e) e = p;
                    }
                }
                #pragma unroll
                for (int m = 1; m < 16; m <<= 1) {
                    unsigned long long o = __shfl_xor(e, m, 64);
                    if (o > e) e = o;
                }
                if (lm == 0) cs[row][wc] = e;
            }
        __syncthreads();
        if (tid < 64) {
            unsigned long long e = cs[tid][0];
            if (cs[tid][1] > e) e = cs[tid][1];
            cand[(size_t)tid * 157 + bx] = e;
        }
    } else {
        // ---------------- L0 path for step t+1: A=h1 splits, W=Whh0 hi ----------------
        const int u = bx - 157;            // 0..255
        const int q = u >> 6;              // K-quarter
        const int nt = u & 63;
        const int n0 = nt * 64 + wc * 32;
        const int m0 = wr * 32;
        const int kbase = q * 256;
        f32x4 acc[2][2] = {};
        f32x4 accL[2][2] = {};
        const f16* a_h = h1h + (size_t)(m0 + lm) * HDIM + kbase + quad * 8;
        const f16* a_l = h1l + (size_t)(m0 + lm) * HDIM + kbase + quad * 8;
        const f16* b_h = Whh0h + (size_t)(n0 + lm) * HDIM + kbase + quad * 8;

        #pragma unroll 4
        for (int ko = 0; ko < 256; ko += 32) {
            f16x8 ah0 = *(const f16x8*)(a_h + ko);
            f16x8 ah1 = *(const f16x8*)(a_h + 16 * HDIM + ko);
            f16x8 al0 = *(const f16x8*)(a_l + ko);
            f16x8 al1 = *(const f16x8*)(a_l + 16 * HDIM + ko);
            f16x8 bh0 = *(const f16x8*)(b_h + ko);
            f16x8 bh1 = *(const f16x8*)(b_h + 16 * HDIM + ko);

            acc[0][0] = __builtin_amdgcn_mfma_f32_16x16x32_f16(ah0, bh0, acc[0][0], 0, 0, 0);
            acc[0][1] = __builtin_amdgcn_mfma_f32_16x16x32_f16(ah0, bh1, acc[0][1], 0, 0, 0);
            acc[1][0] = __builtin_amdgcn_mfma_f32_16x16x32_f16(ah1, bh0, acc[1][0], 0, 0, 0);
            acc[1][1] = __builtin_amdgcn_mfma_f32_16x16x32_f16(ah1, bh1, acc[1][1], 0, 0, 0);

            accL[0][0] = __builtin_amdgcn_mfma_f32_16x16x32_f16(al0, bh0, accL[0][0], 0, 0, 0);
            accL[0][1] = __builtin_amdgcn_mfma_f32_16x16x32_f16(al0, bh1, accL[0][1], 0, 0, 0);
            accL[1][0] = __builtin_amdgcn_mfma_f32_16x16x32_f16(al1, bh0, accL[1][0], 0, 0, 0);
            accL[1][1] = __builtin_amdgcn_mfma_f32_16x16x32_f16(al1, bh1, accL[1][1], 0, 0, 0);
        }

        float* dst = pre0 + (size_t)q * 262144;
        #pragma unroll
        for (int rt = 0; rt < 2; rt++)
            #pragma unroll
            for (int ct = 0; ct < 2; ct++)
                #pragma unroll
                for (int r = 0; r < 4; r++) {
                    int row = m0 + rt * 16 + quad * 4 + r;
                    int col = n0 + ct * 16 + lm;
                    dst[(size_t)row * 4096 + col] =
                        acc[rt][ct][r] + accL[rt][ct][r] * (1.0f / 2048.0f);
                }
    }
}

// Elementwise fp32 -> fp16 hi (+ optional lo*2048); zero-pads past n_src.
__global__ __launch_bounds__(256) void convert_split(
    const float* __restrict__ src, f16* __restrict__ hi, f16* __restrict__ lo,
    int n_src, int n_pad)
{
    int i = blockIdx.x * 256 + threadIdx.x;
    if (i >= n_pad) return;
    float x = (i < n_src) ? src[i] : 0.0f;
    f16 h = (f16)x;
    hi[i] = h;
    if (lo) lo[i] = (f16)((x - (float)h) * 2048.0f);
}

// Layer-0 cell update: token select (cand-reduce / teacher forcing), gates,
// h1 split. 256 blocks x 256 threads; block covers one batch row quarter.
__global__ __launch_bounds__(256) void cell0_kernel(
    const float* __restrict__ part,
    const float* __restrict__ Wih0, const float* __restrict__ bih,
    const float* __restrict__ bhh,
    const int* __restrict__ captions, const int* __restrict__ tfmask,
    const unsigned long long* __restrict__ cand,
    float* __restrict__ c1, f16* __restrict__ h1h, f16* __restrict__ h1l, int t)
{
    int tid = threadIdx.x;
    int idx = blockIdx.x * 256 + tid;
    int b = idx >> 10, i = idx & 1023;
    int tok;
    if (t == 1) {
        tok = captions[b * TDIM];
    } else if (tfmask[t - 1]) {
        tok = captions[b * TDIM + (t - 1)];
    } else {
        __shared__ unsigned long long red[4];
        __shared__ int tok_s;
        unsigned long long e = (tid < 157) ? cand[(size_t)b * 157 + tid] : 0ull;
        #pragma unroll
        for (int m = 32; m > 0; m >>= 1) {
            unsigned long long o = __shfl_down(e, m, 64);
            if (o > e) e = o;
        }
        if ((tid & 63) == 0) red[tid >> 6] = e;
        __syncthreads();
        if (tid == 0) {
            e = red[0];
            if (red[1] > e) e = red[1];
            if (red[2] > e) e = red[2];
            if (red[3] > e) e = red[3];
            tok_s = (int)(~(unsigned)(e & 0xffffffffull));
        }
        __syncthreads();
        tok = tok_s;
    }

    float g[4];
    #pragma unroll
    for (int gi = 0; gi < 4; gi++) {
        int j = gi * HDIM + i;
        float s = bih[j] + bhh[j] + Wih0[(size_t)j * VDIM + tok];
        #pragma unroll
        for (int q = 0; q < 4; q++) s += part[(size_t)q * 262144 + b * 4096 + j];
        g[gi] = s;
    }
    float ig = sigmoidf_(g[0]), fg = sigmoidf_(g[1]);
    float gg = tanhf(g[2]),     og = sigmoidf_(g[3]);
    float cn = fg * c1[idx] + ig * gg;
    float hn = og * tanhf(cn);
    c1[idx] = cn;
    f16 hh = (f16)hn;
    h1h[idx] = hh;
    h1l[idx] = (f16)((hn - (float)hh) * 2048.0f);
}

// Layer-1 cell update; emits fp16 hi/lo split of new h2.
__global__ __launch_bounds__(256) void cell1_kernel(
    const float* __restrict__ part,
    const float* __restrict__ bih, const float* __restrict__ bhh,
    float* __restrict__ c2, f16* __restrict__ h2h, f16* __restrict__ h2l)
{
    int idx = blockIdx.x * 256 + threadIdx.x;
    int b = idx >> 10, i = idx & 1023;
    float g[4];
    #pragma unroll
    for (int gi = 0; gi < 4; gi++) {
        int j = gi * HDIM + i;
        float s = bih[j] + bhh[j];
        #pragma unroll
        for (int q = 0; q < 8; q++) s += part[(size_t)q * 262144 + b * 4096 + j];
        g[gi] = s;
    }
    float ig = sigmoidf_(g[0]), fg = sigmoidf_(g[1]);
    float gg = tanhf(g[2]),     og = sigmoidf_(g[3]);
    float cn = fg * c2[idx] + ig * gg;
    float hn = og * tanhf(cn);
    c2[idx] = cn;
    f16 hh = (f16)hn;
    h2h[idx] = hh;
    h2l[idx] = (f16)((hn - (float)hh) * 2048.0f);
}

// Copy initial states (fp16 splits + fp32 cells), write out[:,0,:] = one_hot.
__global__ __launch_bounds__(256) void init_kernel(
    const float* __restrict__ hidden, const float* __restrict__ cell,
    const int* __restrict__ captions,
    float* __restrict__ c1, float* __restrict__ c2,
    f16* __restrict__ h1h, f16* __restrict__ h1l,
    f16* __restrict__ h2h, f16* __restrict__ h2l,
    float* __restrict__ out)
{
    int idx = blockIdx.x * 256 + threadIdx.x;
    if (idx < BDIM * HDIM) {
        float a = hidden[idx];
        float b = hidden[BDIM * HDIM + idx];
        c1[idx] = cell[idx];
        c2[idx] = cell[BDIM * HDIM + idx];
        f16 ah = (f16)a;
        h1h[idx] = ah; h1l[idx] = (f16)((a - (float)ah) * 2048.0f);
        f16 bh = (f16)b;
        h2h[idx] = bh; h2l[idx] = (f16)((b - (float)bh) * 2048.0f);
    }
    if (idx < BDIM * VDIM) {
        int b = idx / VDIM, v = idx % VDIM;
        out[(size_t)b * TDIM * VDIM + v] = (v == captions[b * TDIM]) ? 1.0f : 0.0f;
    }
}

extern "C" void kernel_launch(void* const* d_in, const int* in_sizes, int n_in,
                              void* d_out, int out_size, void* d_ws, size_t ws_size,
                              hipStream_t stream)
{
    const float* hidden   = (const float*)d_in[0];
    const float* cellin   = (const float*)d_in[1];
    const int*   captions = (const int*)d_in[2];
    const int*   tfmask   = (const int*)d_in[3];
    const float* Wih0 = (const float*)d_in[4];
    const float* Whh0 = (const float*)d_in[5];
    const float* bih0 = (const float*)d_in[6];
    const float* bhh0 = (const float*)d_in[7];
    const float* Wih1 = (const float*)d_in[8];
    const float* Whh1 = (const float*)d_in[9];
    const float* bih1 = (const float*)d_in[10];
    const float* bhh1 = (const float*)d_in[11];
    const float* Wout = (const float*)d_in[12];
    const float* bout = (const float*)d_in[13];
    float* out = (float*)d_out;

    char* wsb = (char*)d_ws;
    float* c1 = (float*)(wsb + WS_C1);
    float* c2 = (float*)(wsb + WS_C2);
    f16* h1h = (f16*)(wsb + WS_H1H);
    f16* h1l = (f16*)(wsb + WS_H1L);
    f16* h2h = (f16*)(wsb + WS_H2H);
    f16* h2l = (f16*)(wsb + WS_H2L);
    unsigned long long* cand = (unsigned long long*)(wsb + WS_CAND);
    float* pre0 = (float*)(wsb + WS_PRE0);
    float* pre1 = (float*)(wsb + WS_PRE1);
    f16* Whh0h = (f16*)(wsb + WS_WB);
    f16* Wih1h = (f16*)(wsb + WS_WB + 1 * (size_t)SQB);
    f16* Whh1h = (f16*)(wsb + WS_WB + 2 * (size_t)SQB);
    f16* Wouth = (f16*)(wsb + WS_WB + 3 * (size_t)SQB);
    f16* Woutl = (f16*)(wsb + WS_WB + 3 * (size_t)SQB + (size_t)WVO);

    // ---------------- one-time: init + weight conversion ----------------
    init_kernel<<<2500, 256, 0, stream>>>(hidden, cellin, captions,
                                          c1, c2, h1h, h1l, h2h, h2l, out);
    int nsq = 4096 * 1024;
    convert_split<<<nsq / 256, 256, 0, stream>>>(Whh0, Whh0h, (f16*)0, nsq, nsq);
    convert_split<<<nsq / 256, 256, 0, stream>>>(Wih1, Wih1h, (f16*)0, nsq, nsq);
    convert_split<<<nsq / 256, 256, 0, stream>>>(Whh1, Whh1h, (f16*)0, nsq, nsq);
    int nvo = VPAD * 1024;
    convert_split<<<nvo / 256, 256, 0, stream>>>(Wout, Wouth, Woutl,
                                                 VDIM * 1024, nvo);

    // prologue: L0 h-gemm for t=1
    gemm_as<<<dim3(64, 4, 1), 256, 0, stream>>>(
        h1h, h1l, Whh0h, h1h, h1l, Whh0h, pre0, 4);

    for (int t = 1; t < TDIM; t++) {
        cell0_kernel<<<256, 256, 0, stream>>>(pre0, Wih0, bih0, bhh0,
                                              captions, tfmask, cand,
                                              c1, h1h, h1l, t);
        gemm_as<<<dim3(64, 4, 2), 256, 0, stream>>>(
            h1h, h1l, Wih1h, h2h, h2l, Whh1h, pre1, 4);
        cell1_kernel<<<256, 256, 0, stream>>>(pre1, bih1, bhh1, c2, h2h, h2l);
        int nb = (t < TDIM - 1) ? 413 : 157;
        gemm_out_l0<<<nb, 256, 0, stream>>>(h2h, h2l, Wouth, Woutl, bout,
                                            out, cand, t,
                                            h1h, h1l, Whh0h, pre0);
    }
}

// Round 6
// 2188.580 us; speedup vs baseline: 5.1139x; 1.0671x over previous
//
#include <hip/hip_runtime.h>

// TextDecoder: 2-layer LSTM, B=64, H=1024, V=10000, T=32 (31 computed steps).
// Round 7: round-5 launched structure (2335 us, proven) +
//  - Wout stored FRAGMENT-CONTIGUOUS (swizzle proven correct on HW in round 4):
//    logits B-loads become contiguous 1 KB wave bursts instead of 16 lines
//    scattered 2 KB apart (miss-concurrency cap suspected at ~1.4 TB/s).
//    Logits kernel: 157 blocks x 4 waves (2 n-tiles x 2 K-halves), K-halves
//    combined via LDS, fused out+bias+argmax-candidate epilogue.
//  - KS 4->2 for L0/L1 partial GEMMs: partial round-trip 24 -> 12 MB/step.
//  - Everything else identical to round 5.

#define HDIM 1024
#define BDIM 64
#define VDIM 10000
#define VPAD 10048   // 314 * 32
#define NTOUT 314    // 32-col n-tiles in Wout
#define TDIM 32

typedef _Float16 f16;
typedef _Float16 f16x8 __attribute__((ext_vector_type(8)));
typedef float f32x4 __attribute__((ext_vector_type(4)));

// ---- workspace layout (bytes); total ~73.9 MB <= proven ws_size >= 101,450,752
#define WS_C1    0              // 64x1024 f32
#define WS_C2    262144
#define WS_H1H   524288         // 64x1024 f16 each
#define WS_H1L   655360
#define WS_H2H   786432
#define WS_H2L   917504
#define WS_CAND  1048576        // 64 x 314 u64 candidates (160,768 B)
#define WS_PRE0  1212416        // 2 slabs x [64][4096] f32 (L0 partials, KS=2)
#define WS_PRE1  3309568        // 4 slabs x [64][4096] f32 (L1 partials, KS=2 x2)
#define WS_WB    7503872        // converted weights
#define SQB      8388608        // 4096x1024 f16 (plain layout)
#define WVO      20578304       // swizzled VPADx1024 f16

__device__ __forceinline__ float sigmoidf_(float x) {
    return 1.0f / (1.0f + expf(-x));
}

// ------------------------------------------------------------------
// Plain-layout A-split GEMM: part[slab] = A(hi+lo/2048) @ W(hi)^T, K-piece q.
// Block = 64x64 tile (2x2 waves of 32x32), fragments straight from global.
// C layout (HW-verified): row = m0 + rt*16 + quad*4 + r, col = n0 + ct*16 + lm.
// ------------------------------------------------------------------
__global__ __launch_bounds__(256) void gemm_as(
    const f16* __restrict__ Ah0, const f16* __restrict__ Al0,
    const f16* __restrict__ Wh0,
    const f16* __restrict__ Ah1, const f16* __restrict__ Al1,
    const f16* __restrict__ Wh1,
    float* __restrict__ part, int KS)
{
    const int tid = threadIdx.x;
    const int wave = tid >> 6, lane = tid & 63;
    const int wr = wave >> 1, wc = wave & 1;
    const int q = blockIdx.y, z = blockIdx.z;
    const f16* __restrict__ Ah = z ? Ah1 : Ah0;
    const f16* __restrict__ Al = z ? Al1 : Al0;
    const f16* __restrict__ Wh = z ? Wh1 : Wh0;
    const int klen = HDIM / KS;
    const int kbase = q * klen;
    const int n0 = blockIdx.x * 64 + wc * 32;
    const int m0 = wr * 32;
    const int lm = lane & 15, quad = lane >> 4;
    const int slab = z * KS + q;

    f32x4 acc[2][2] = {};
    f32x4 accL[2][2] = {};

    const f16* a_h = Ah + (size_t)(m0 + lm) * HDIM + kbase + quad * 8;
    const f16* a_l = Al + (size_t)(m0 + lm) * HDIM + kbase + quad * 8;
    const f16* b_h = Wh + (size_t)(n0 + lm) * HDIM + kbase + quad * 8;

    #pragma unroll 4
    for (int ko = 0; ko < klen; ko += 32) {
        f16x8 ah0 = *(const f16x8*)(a_h + ko);
        f16x8 ah1 = *(const f16x8*)(a_h + 16 * HDIM + ko);
        f16x8 al0 = *(const f16x8*)(a_l + ko);
        f16x8 al1 = *(const f16x8*)(a_l + 16 * HDIM + ko);
        f16x8 bh0 = *(const f16x8*)(b_h + ko);
        f16x8 bh1 = *(const f16x8*)(b_h + 16 * HDIM + ko);

        acc[0][0] = __builtin_amdgcn_mfma_f32_16x16x32_f16(ah0, bh0, acc[0][0], 0, 0, 0);
        acc[0][1] = __builtin_amdgcn_mfma_f32_16x16x32_f16(ah0, bh1, acc[0][1], 0, 0, 0);
        acc[1][0] = __builtin_amdgcn_mfma_f32_16x16x32_f16(ah1, bh0, acc[1][0], 0, 0, 0);
        acc[1][1] = __builtin_amdgcn_mfma_f32_16x16x32_f16(ah1, bh1, acc[1][1], 0, 0, 0);

        accL[0][0] = __builtin_amdgcn_mfma_f32_16x16x32_f16(al0, bh0, accL[0][0], 0, 0, 0);
        accL[0][1] = __builtin_amdgcn_mfma_f32_16x16x32_f16(al0, bh1, accL[0][1], 0, 0, 0);
        accL[1][0] = __builtin_amdgcn_mfma_f32_16x16x32_f16(al1, bh0, accL[1][0], 0, 0, 0);
        accL[1][1] = __builtin_amdgcn_mfma_f32_16x16x32_f16(al1, bh1, accL[1][1], 0, 0, 0);
    }

    float* dst = part + (size_t)slab * 262144;
    #pragma unroll
    for (int rt = 0; rt < 2; rt++)
        #pragma unroll
        for (int ct = 0; ct < 2; ct++)
            #pragma unroll
            for (int r = 0; r < 4; r++) {
                int row = m0 + rt * 16 + quad * 4 + r;
                int col = n0 + ct * 16 + lm;
                dst[(size_t)row * 4096 + col] =
                    acc[rt][ct][r] + accL[rt][ct][r] * (1.0f / 2048.0f);
            }
}

// ------------------------------------------------------------------
// Fused kernel.
// Blocks 0..156: logits with SWIZZLED Wout (hi+lo). 4 waves = 2 n-tiles x
//   2 K-halves; K-halves combined via LDS; epilogue writes out+bias and
//   per-32-col argmax candidates.
// Blocks 157..284: L0 h-gemm for step t+1 (plain layout, KS=2 -> pre0).
// Swizzle layout (HW-verified round 4): f16 index
//   nt*32768 + kb*1024 + c*512 + lane*8 + e
//   <-> row = nt*32 + c*16 + (lane&15), col = kb*32 + (lane>>4)*8 + e.
// ------------------------------------------------------------------
__global__ __launch_bounds__(256) void gemm_out_l0(
    const f16* __restrict__ h2h, const f16* __restrict__ h2l,
    const f16* __restrict__ Wsh, const f16* __restrict__ Wsl,
    const float* __restrict__ bout, float* __restrict__ out,
    unsigned long long* __restrict__ cand, int t,
    const f16* __restrict__ h1h, const f16* __restrict__ h1l,
    const f16* __restrict__ Whh0h, float* __restrict__ pre0)
{
    const int tid = threadIdx.x, bx = blockIdx.x;
    const int wave = tid >> 6, lane = tid & 63;
    const int lm = lane & 15, quad = lane >> 4;

    if (bx < 157) {
        // ---------------- swizzled logits path ----------------
        const int tl = wave & 1;         // tile slot in block
        const int kh = wave >> 1;        // K-half
        const int gt = bx * 2 + tl;      // global n-tile, 0..313
        f32x4 acc[4][2] = {};
        f32x4 accL[4][2] = {};
        const f16* a_h = h2h + (size_t)lm * HDIM + kh * 512 + quad * 8;
        const f16* a_l = h2l + (size_t)lm * HDIM + kh * 512 + quad * 8;
        const f16* w_h = Wsh + (size_t)gt * 32768 + (size_t)kh * 16384 + lane * 8;
        const f16* w_l = Wsl + (size_t)gt * 32768 + (size_t)kh * 16384 + lane * 8;

        #pragma unroll 4
        for (int kb = 0; kb < 16; kb++) {
            f16x8 bh0 = *(const f16x8*)(w_h + kb * 1024);
            f16x8 bh1 = *(const f16x8*)(w_h + kb * 1024 + 512);
            f16x8 bl0 = *(const f16x8*)(w_l + kb * 1024);
            f16x8 bl1 = *(const f16x8*)(w_l + kb * 1024 + 512);
            f16x8 ah[4], al[4];
            #pragma unroll
            for (int mt = 0; mt < 4; mt++) {
                ah[mt] = *(const f16x8*)(a_h + mt * (16 * HDIM) + kb * 32);
                al[mt] = *(const f16x8*)(a_l + mt * (16 * HDIM) + kb * 32);
            }
            #pragma unroll
            for (int mt = 0; mt < 4; mt++) {
                acc[mt][0]  = __builtin_amdgcn_mfma_f32_16x16x32_f16(ah[mt], bh0, acc[mt][0], 0, 0, 0);
                acc[mt][1]  = __builtin_amdgcn_mfma_f32_16x16x32_f16(ah[mt], bh1, acc[mt][1], 0, 0, 0);
                accL[mt][0] = __builtin_amdgcn_mfma_f32_16x16x32_f16(al[mt], bh0, accL[mt][0], 0, 0, 0);
                accL[mt][1] = __builtin_amdgcn_mfma_f32_16x16x32_f16(al[mt], bh1, accL[mt][1], 0, 0, 0);
                accL[mt][0] = __builtin_amdgcn_mfma_f32_16x16x32_f16(ah[mt], bl0, accL[mt][0], 0, 0, 0);
                accL[mt][1] = __builtin_amdgcn_mfma_f32_16x16x32_f16(ah[mt], bl1, accL[mt][1], 0, 0, 0);
            }
        }

        // combine hi + lo/2048 per K-half
        float part_[4][2][4];
        #pragma unroll
        for (int mt = 0; mt < 4; mt++)
            #pragma unroll
            for (int c = 0; c < 2; c++)
                #pragma unroll
                for (int r = 0; r < 4; r++)
                    part_[mt][c][r] = acc[mt][c][r] + accL[mt][c][r] * (1.0f / 2048.0f);

        __shared__ float lds[2][64][33];
        if (kh == 1) {
            #pragma unroll
            for (int mt = 0; mt < 4; mt++)
                #pragma unroll
                for (int c = 0; c < 2; c++)
                    #pragma unroll
                    for (int r = 0; r < 4; r++)
                        lds[tl][mt * 16 + quad * 4 + r][c * 16 + lm] = part_[mt][c][r];
        }
        __syncthreads();
        if (kh == 0) {
            float bo[2];
            #pragma unroll
            for (int c = 0; c < 2; c++) {
                int col = gt * 32 + c * 16 + lm;
                bo[c] = (col < VDIM) ? bout[col] : 0.0f;
            }
            #pragma unroll
            for (int mt = 0; mt < 4; mt++)
                #pragma unroll
                for (int r = 0; r < 4; r++) {
                    int row = mt * 16 + quad * 4 + r;
                    unsigned long long e = 0ull;
                    #pragma unroll
                    for (int c = 0; c < 2; c++) {
                        int col = gt * 32 + c * 16 + lm;
                        float sv = part_[mt][c][r] + lds[tl][row][c * 16 + lm] + bo[c];
                        if (col < VDIM) {
                            out[(size_t)row * (TDIM * VDIM) + (size_t)t * VDIM + col] = sv;
                            unsigned u = __float_as_uint(sv);
                            u = (u & 0x80000000u) ? ~u : (u | 0x80000000u);
                            unsigned long long p =
                                ((unsigned long long)u << 32) | (unsigned)(~col);
                            if (p > e) e = p;
                        }
                    }
                    // reduce across the 16 lm lanes (same quad group)
                    #pragma unroll
                    for (int m = 1; m < 16; m <<= 1) {
                        unsigned long long o = __shfl_xor(e, m, 64);
                        if (o > e) e = o;
                    }
                    if (lm == 0) cand[(size_t)row * NTOUT + gt] = e;
                }
        }
    } else {
        // ---------------- L0 path for step t+1 (plain layout, KS=2) ----------------
        const int wr = wave >> 1, wc = wave & 1;
        const int u = bx - 157;            // 0..127
        const int q = u >> 6;              // K-half
        const int nt = u & 63;
        const int n0 = nt * 64 + wc * 32;
        const int m0 = wr * 32;
        const int kbase = q * 512;
        f32x4 acc[2][2] = {};
        f32x4 accL[2][2] = {};
        const f16* a_h = h1h + (size_t)(m0 + lm) * HDIM + kbase + quad * 8;
        const f16* a_l = h1l + (size_t)(m0 + lm) * HDIM + kbase + quad * 8;
        const f16* b_h = Whh0h + (size_t)(n0 + lm) * HDIM + kbase + quad * 8;

        #pragma unroll 4
        for (int ko = 0; ko < 512; ko += 32) {
            f16x8 ah0 = *(const f16x8*)(a_h + ko);
            f16x8 ah1 = *(const f16x8*)(a_h + 16 * HDIM + ko);
            f16x8 al0 = *(const f16x8*)(a_l + ko);
            f16x8 al1 = *(const f16x8*)(a_l + 16 * HDIM + ko);
            f16x8 bh0 = *(const f16x8*)(b_h + ko);
            f16x8 bh1 = *(const f16x8*)(b_h + 16 * HDIM + ko);

            acc[0][0] = __builtin_amdgcn_mfma_f32_16x16x32_f16(ah0, bh0, acc[0][0], 0, 0, 0);
            acc[0][1] = __builtin_amdgcn_mfma_f32_16x16x32_f16(ah0, bh1, acc[0][1], 0, 0, 0);
            acc[1][0] = __builtin_amdgcn_mfma_f32_16x16x32_f16(ah1, bh0, acc[1][0], 0, 0, 0);
            acc[1][1] = __builtin_amdgcn_mfma_f32_16x16x32_f16(ah1, bh1, acc[1][1], 0, 0, 0);

            accL[0][0] = __builtin_amdgcn_mfma_f32_16x16x32_f16(al0, bh0, accL[0][0], 0, 0, 0);
            accL[0][1] = __builtin_amdgcn_mfma_f32_16x16x32_f16(al0, bh1, accL[0][1], 0, 0, 0);
            accL[1][0] = __builtin_amdgcn_mfma_f32_16x16x32_f16(al1, bh0, accL[1][0], 0, 0, 0);
            accL[1][1] = __builtin_amdgcn_mfma_f32_16x16x32_f16(al1, bh1, accL[1][1], 0, 0, 0);
        }

        float* dst = pre0 + (size_t)q * 262144;
        #pragma unroll
        for (int rt = 0; rt < 2; rt++)
            #pragma unroll
            for (int ct = 0; ct < 2; ct++)
                #pragma unroll
                for (int r = 0; r < 4; r++) {
                    int row = m0 + rt * 16 + quad * 4 + r;
                    int col = n0 + ct * 16 + lm;
                    dst[(size_t)row * 4096 + col] =
                        acc[rt][ct][r] + accL[rt][ct][r] * (1.0f / 2048.0f);
                }
    }
}

// Elementwise fp32 -> fp16 hi (plain layout).
__global__ __launch_bounds__(256) void convert_hi(
    const float* __restrict__ src, f16* __restrict__ hi, int n)
{
    int i = blockIdx.x * 256 + threadIdx.x;
    if (i >= n) return;
    hi[i] = (f16)src[i];
}

// Wout fp32 [VDIM x 1024] -> swizzled hi + lo*2048, zero-padded to NTOUT tiles.
// (Mapping HW-verified in round 4.)
__global__ __launch_bounds__(256) void conv_swz_out(
    const float* __restrict__ src, f16* __restrict__ hi, f16* __restrict__ lo)
{
    int o = blockIdx.x * 256 + threadIdx.x;     // octet index
    if (o >= NTOUT * 4096) return;
    int lane = o & 63, c = (o >> 6) & 1, kb = (o >> 7) & 31, nt = o >> 12;
    int row = nt * 32 + c * 16 + (lane & 15);
    int col = kb * 32 + ((lane >> 4) << 3);
    float f[8] = {};
    if (row < VDIM) {
        float4 v0 = *(const float4*)(src + (size_t)row * HDIM + col);
        float4 v1 = *(const float4*)(src + (size_t)row * HDIM + col + 4);
        f[0] = v0.x; f[1] = v0.y; f[2] = v0.z; f[3] = v0.w;
        f[4] = v1.x; f[5] = v1.y; f[6] = v1.z; f[7] = v1.w;
    }
    f16x8 H, L;
    #pragma unroll
    for (int e = 0; e < 8; e++) {
        f16 h = (f16)f[e];
        H[e] = h;
        L[e] = (f16)((f[e] - (float)h) * 2048.0f);
    }
    *(f16x8*)(hi + (size_t)o * 8) = H;
    *(f16x8*)(lo + (size_t)o * 8) = L;
}

// Layer-0 cell update: token select (cand-reduce / teacher forcing), gates,
// h1 split. 256 blocks x 256 threads.
__global__ __launch_bounds__(256) void cell0_kernel(
    const float* __restrict__ part,
    const float* __restrict__ Wih0, const float* __restrict__ bih,
    const float* __restrict__ bhh,
    const int* __restrict__ captions, const int* __restrict__ tfmask,
    const unsigned long long* __restrict__ cand,
    float* __restrict__ c1, f16* __restrict__ h1h, f16* __restrict__ h1l, int t)
{
    int tid = threadIdx.x;
    int idx = blockIdx.x * 256 + tid;
    int b = idx >> 10, i = idx & 1023;
    int tok;
    if (t == 1) {
        tok = captions[b * TDIM];
    } else if (tfmask[t - 1]) {
        tok = captions[b * TDIM + (t - 1)];
    } else {
        __shared__ unsigned long long red[4];
        __shared__ int tok_s;
        unsigned long long e = 0ull;
        if (tid < 157) {
            e = cand[(size_t)b * NTOUT + tid];
            unsigned long long e2 = cand[(size_t)b * NTOUT + 157 + tid];
            if (e2 > e) e = e2;
        }
        #pragma unroll
        for (int m = 32; m > 0; m >>= 1) {
            unsigned long long o = __shfl_down(e, m, 64);
            if (o > e) e = o;
        }
        if ((tid & 63) == 0) red[tid >> 6] = e;
        __syncthreads();
        if (tid == 0) {
            e = red[0];
            if (red[1] > e) e = red[1];
            if (red[2] > e) e = red[2];
            if (red[3] > e) e = red[3];
            tok_s = (int)(~(unsigned)(e & 0xffffffffull));
        }
        __syncthreads();
        tok = tok_s;
    }

    float g[4];
    #pragma unroll
    for (int gi = 0; gi < 4; gi++) {
        int j = gi * HDIM + i;
        float s = bih[j] + bhh[j] + Wih0[(size_t)j * VDIM + tok];
        #pragma unroll
        for (int q = 0; q < 2; q++) s += part[(size_t)q * 262144 + b * 4096 + j];
        g[gi] = s;
    }
    float ig = sigmoidf_(g[0]), fg = sigmoidf_(g[1]);
    float gg = tanhf(g[2]),     og = sigmoidf_(g[3]);
    float cn = fg * c1[idx] + ig * gg;
    float hn = og * tanhf(cn);
    c1[idx] = cn;
    f16 hh = (f16)hn;
    h1h[idx] = hh;
    h1l[idx] = (f16)((hn - (float)hh) * 2048.0f);
}

// Layer-1 cell update; emits fp16 hi/lo split of new h2.
__global__ __launch_bounds__(256) void cell1_kernel(
    const float* __restrict__ part,
    const float* __restrict__ bih, const float* __restrict__ bhh,
    float* __restrict__ c2, f16* __restrict__ h2h, f16* __restrict__ h2l)
{
    int idx = blockIdx.x * 256 + threadIdx.x;
    int b = idx >> 10, i = idx & 1023;
    float g[4];
    #pragma unroll
    for (int gi = 0; gi < 4; gi++) {
        int j = gi * HDIM + i;
        float s = bih[j] + bhh[j];
        #pragma unroll
        for (int q = 0; q < 4; q++) s += part[(size_t)q * 262144 + b * 4096 + j];
        g[gi] = s;
    }
    float ig = sigmoidf_(g[0]), fg = sigmoidf_(g[1]);
    float gg = tanhf(g[2]),     og = sigmoidf_(g[3]);
    float cn = fg * c2[idx] + ig * gg;
    float hn = og * tanhf(cn);
    c2[idx] = cn;
    f16 hh = (f16)hn;
    h2h[idx] = hh;
    h2l[idx] = (f16)((hn - (float)hh) * 2048.0f);
}

// Copy initial states (fp16 splits + fp32 cells), write out[:,0,:] = one_hot.
__global__ __launch_bounds__(256) void init_kernel(
    const float* __restrict__ hidden, const float* __restrict__ cell,
    const int* __restrict__ captions,
    float* __restrict__ c1, float* __restrict__ c2,
    f16* __restrict__ h1h, f16* __restrict__ h1l,
    f16* __restrict__ h2h, f16* __restrict__ h2l,
    float* __restrict__ out)
{
    int idx = blockIdx.x * 256 + threadIdx.x;
    if (idx < BDIM * HDIM) {
        float a = hidden[idx];
        float b = hidden[BDIM * HDIM + idx];
        c1[idx] = cell[idx];
        c2[idx] = cell[BDIM * HDIM + idx];
        f16 ah = (f16)a;
        h1h[idx] = ah; h1l[idx] = (f16)((a - (float)ah) * 2048.0f);
        f16 bh = (f16)b;
        h2h[idx] = bh; h2l[idx] = (f16)((b - (float)bh) * 2048.0f);
    }
    if (idx < BDIM * VDIM) {
        int b = idx / VDIM, v = idx % VDIM;
        out[(size_t)b * TDIM * VDIM + v] = (v == captions[b * TDIM]) ? 1.0f : 0.0f;
    }
}

extern "C" void kernel_launch(void* const* d_in, const int* in_sizes, int n_in,
                              void* d_out, int out_size, void* d_ws, size_t ws_size,
                              hipStream_t stream)
{
    const float* hidden   = (const float*)d_in[0];
    const float* cellin   = (const float*)d_in[1];
    const int*   captions = (const int*)d_in[2];
    const int*   tfmask   = (const int*)d_in[3];
    const float* Wih0 = (const float*)d_in[4];
    const float* Whh0 = (const float*)d_in[5];
    const float* bih0 = (const float*)d_in[6];
    const float* bhh0 = (const float*)d_in[7];
    const float* Wih1 = (const float*)d_in[8];
    const float* Whh1 = (const float*)d_in[9];
    const float* bih1 = (const float*)d_in[10];
    const float* bhh1 = (const float*)d_in[11];
    const float* Wout = (const float*)d_in[12];
    const float* bout = (const float*)d_in[13];
    float* out = (float*)d_out;

    char* wsb = (char*)d_ws;
    float* c1 = (float*)(wsb + WS_C1);
    float* c2 = (float*)(wsb + WS_C2);
    f16* h1h = (f16*)(wsb + WS_H1H);
    f16* h1l = (f16*)(wsb + WS_H1L);
    f16* h2h = (f16*)(wsb + WS_H2H);
    f16* h2l = (f16*)(wsb + WS_H2L);
    unsigned long long* cand = (unsigned long long*)(wsb + WS_CAND);
    float* pre0 = (float*)(wsb + WS_PRE0);
    float* pre1 = (float*)(wsb + WS_PRE1);
    f16* Whh0h = (f16*)(wsb + WS_WB);
    f16* Wih1h = (f16*)(wsb + WS_WB + 1 * (size_t)SQB);
    f16* Whh1h = (f16*)(wsb + WS_WB + 2 * (size_t)SQB);
    f16* Wouth = (f16*)(wsb + WS_WB + 3 * (size_t)SQB);
    f16* Woutl = (f16*)(wsb + WS_WB + 3 * (size_t)SQB + (size_t)WVO);

    // ---------------- one-time: init + weight conversion ----------------
    init_kernel<<<2500, 256, 0, stream>>>(hidden, cellin, captions,
                                          c1, c2, h1h, h1l, h2h, h2l, out);
    int nsq = 4096 * 1024;
    convert_hi<<<nsq / 256, 256, 0, stream>>>(Whh0, Whh0h, nsq);
    convert_hi<<<nsq / 256, 256, 0, stream>>>(Wih1, Wih1h, nsq);
    convert_hi<<<nsq / 256, 256, 0, stream>>>(Whh1, Whh1h, nsq);
    conv_swz_out<<<(NTOUT * 4096 + 255) / 256, 256, 0, stream>>>(Wout, Wouth, Woutl);

    // prologue: L0 h-gemm for t=1 (KS=2)
    gemm_as<<<dim3(64, 2, 1), 256, 0, stream>>>(
        h1h, h1l, Whh0h, h1h, h1l, Whh0h, pre0, 2);

    for (int t = 1; t < TDIM; t++) {
        cell0_kernel<<<256, 256, 0, stream>>>(pre0, Wih0, bih0, bhh0,
                                              captions, tfmask, cand,
                                              c1, h1h, h1l, t);
        gemm_as<<<dim3(64, 2, 2), 256, 0, stream>>>(
            h1h, h1l, Wih1h, h2h, h2l, Whh1h, pre1, 2);
        cell1_kernel<<<256, 256, 0, stream>>>(pre1, bih1, bhh1, c2, h2h, h2l);
        int nb = (t < TDIM - 1) ? 285 : 157;
        gemm_out_l0<<<nb, 256, 0, stream>>>(h2h, h2l, Wouth, Woutl, bout,
                                            out, cand, t,
                                            h1h, h1l, Whh0h, pre0);
    }
}